// Round 1
// baseline (110.502 us; speedup 1.0000x reference)
//
#include <hip/hip_runtime.h>
#include <hip/hip_bf16.h>

// Depthwise separable 4x4 blur (upfirdn2d, pad=(2,1), taps [1,3,3,1]/8 per axis).
// x: [16,256,128,128] f32 -> out same shape.
// out[y,x] = sum_{dy,dx in -2..+1} in[y+dy, x+dx] * w[dy]*w[dx], w = {1,3,3,1}/8
// (w[-2]=1, w[-1]=3, w[0]=3, w[+1]=1), zero outside bounds.

#define BLUR_H 128
#define BLUR_W 128

__global__ __launch_bounds__(256) void Blur_28243704938542_kernel(
    const float* __restrict__ in, float* __restrict__ out) {
    const int p     = blockIdx.x;          // plane index (b*C + c)
    const int tid   = threadIdx.x;
    const int colt  = tid & 31;            // thread-column 0..31 (4 cols each)
    const int strip = tid >> 5;            // 0..7 (16 rows each)
    const int xb    = colt << 2;           // 0,4,...,124
    const int y0    = strip << 4;          // 0,16,...,112

    const float* __restrict__ ip = in  + (size_t)p * (BLUR_H * BLUR_W);
    float* __restrict__ op       = out + (size_t)p * (BLUR_H * BLUR_W);

    const bool hasL = (colt != 0);
    const bool hasR = (colt != 31);

    // Horizontal blur (unscaled, weights 1,3,3,1) of input row y for this
    // thread's 4 output columns; zero row if y outside [0,H).
    auto loadrow = [&](int y) -> float4 {
        if ((unsigned)y >= (unsigned)BLUR_H) return make_float4(0.f, 0.f, 0.f, 0.f);
        const float* r = ip + y * BLUR_W + xb;
        const float4 c = *reinterpret_cast<const float4*>(r);
        float lx = 0.f, ly = 0.f, rr = 0.f;
        if (hasL) {  // cols xb-2, xb-1 (8B aligned)
            const float2 l = *reinterpret_cast<const float2*>(r - 2);
            lx = l.x; ly = l.y;
        }
        if (hasR) rr = r[4];  // col xb+4
        float4 h;
        h.x = lx  + 3.f * ly  + 3.f * c.x + c.y;
        h.y = ly  + 3.f * c.x + 3.f * c.y + c.z;
        h.z = c.x + 3.f * c.y + 3.f * c.z + c.w;
        h.w = c.y + 3.f * c.z + 3.f * c.w + rr;
        return h;
    };

    float4 hm2 = loadrow(y0 - 2);
    float4 hm1 = loadrow(y0 - 1);
    float4 h0  = loadrow(y0);

    #pragma unroll
    for (int i = 0; i < 16; ++i) {
        const int y = y0 + i;
        const float4 hp1 = loadrow(y + 1);
        const float s = 1.0f / 64.0f;
        float4 o;
        o.x = (hm2.x + 3.f * hm1.x + 3.f * h0.x + hp1.x) * s;
        o.y = (hm2.y + 3.f * hm1.y + 3.f * h0.y + hp1.y) * s;
        o.z = (hm2.z + 3.f * hm1.z + 3.f * h0.z + hp1.z) * s;
        o.w = (hm2.w + 3.f * hm1.w + 3.f * h0.w + hp1.w) * s;
        *reinterpret_cast<float4*>(op + y * BLUR_W + xb) = o;
        hm2 = hm1; hm1 = h0; h0 = hp1;
    }
}

extern "C" void kernel_launch(void* const* d_in, const int* in_sizes, int n_in,
                              void* d_out, int out_size, void* d_ws, size_t ws_size,
                              hipStream_t stream) {
    const float* x = (const float*)d_in[0];
    // d_in[1] is the 4x4 kernel; its values are fixed ([1,3,3,1] outer /64),
    // baked into the kernel as exact binary constants.
    float* out = (float*)d_out;
    const int planes = 16 * 256;  // B*C
    Blur_28243704938542_kernel<<<planes, 256, 0, stream>>>(x, out);
}

// Round 3
// 85.578 us; speedup vs baseline: 1.2912x; 1.2912x over previous
//
#include <hip/hip_runtime.h>
#include <hip/hip_bf16.h>

// Depthwise separable 4x4 blur (upfirdn2d, pad=(2,1), taps [1,3,3,1]/8 per axis).
// x: [16,256,128,128] f32 -> out same shape.
// out[y,x] = sum_{dy,dx in -2..+1} in[y+dy, x+dx] * w[dy]*w[dx], w = {1,3,3,1}
// (w[-2]=1, w[-1]=3, w[0]=3, w[+1]=1), zero outside bounds, scaled by 1/64.
//
// R3 design (= R2 + compile fix): 64-row strips (read amplification 67/64),
// horizontal halos via cross-lane shuffles (1 vector load per row per thread),
// nontemporal stores via native clang vector type (HIP float4 is a class and
// is rejected by __builtin_nontemporal_store).

#define BLUR_H 128
#define BLUR_W 128

typedef float f32x4 __attribute__((ext_vector_type(4)));

__global__ __launch_bounds__(256) void Blur_28243704938542_kernel(
    const float* __restrict__ in, float* __restrict__ out) {
    const int tid   = threadIdx.x;
    const int g     = tid >> 6;            // plane-group within block (0..3)
    const int lane  = tid & 63;
    const int colt  = lane & 31;           // thread-column 0..31 (4 cols each)
    const int strip = lane >> 5;           // 0..1 (64 rows each)
    const int p     = (blockIdx.x << 2) + g;
    const int xb    = colt << 2;           // 0,4,...,124
    const int y0    = strip << 6;          // 0 or 64

    const float* __restrict__ ip = in  + (size_t)p * (BLUR_H * BLUR_W);
    float* __restrict__ op       = out + (size_t)p * (BLUR_H * BLUR_W);

    const bool hasL = (colt != 0);
    const bool hasR = (colt != 31);

    // Horizontal blur (unscaled, weights 1,3,3,1) of input row y for this
    // thread's 4 output columns. One vector load; halo cols come from
    // neighbor lanes via shuffle. Zero row if y outside [0,H).
    auto loadrow = [&](int y) -> f32x4 {
        f32x4 c = (f32x4)0.f;
        if ((unsigned)y < (unsigned)BLUR_H)
            c = *reinterpret_cast<const f32x4*>(ip + y * BLUR_W + xb);
        // lane-1 holds cols xb-2 (its c.z) and xb-1 (its c.w); lane+1 holds
        // col xb+4 (its c.x). Shuffles run full-wave (load was predicated).
        float lz = __shfl_up(c.z, 1);
        float lw = __shfl_up(c.w, 1);
        float rx = __shfl_down(c.x, 1);
        if (!hasL) { lz = 0.f; lw = 0.f; }
        if (!hasR) { rx = 0.f; }
        f32x4 h;
        h.x = lz  + 3.f * lw  + 3.f * c.x + c.y;
        h.y = lw  + 3.f * c.x + 3.f * c.y + c.z;
        h.z = c.x + 3.f * c.y + 3.f * c.z + c.w;
        h.w = c.y + 3.f * c.z + 3.f * c.w + rx;
        return h;
    };

    f32x4 hm2 = loadrow(y0 - 2);
    f32x4 hm1 = loadrow(y0 - 1);
    f32x4 h0  = loadrow(y0);

    #pragma unroll 4
    for (int i = 0; i < 64; ++i) {
        const int y = y0 + i;
        const f32x4 hp1 = loadrow(y + 1);
        const float s = 1.0f / 64.0f;
        f32x4 o = (hm2 + 3.f * hm1 + 3.f * h0 + hp1) * s;
        __builtin_nontemporal_store(o, reinterpret_cast<f32x4*>(op + y * BLUR_W + xb));
        hm2 = hm1; hm1 = h0; h0 = hp1;
    }
}

extern "C" void kernel_launch(void* const* d_in, const int* in_sizes, int n_in,
                              void* d_out, int out_size, void* d_ws, size_t ws_size,
                              hipStream_t stream) {
    const float* x = (const float*)d_in[0];
    // d_in[1] is the 4x4 kernel; its values are fixed ([1,3,3,1] outer /64),
    // baked in as exact binary constants.
    float* out = (float*)d_out;
    const int planes = 16 * 256;          // B*C = 4096
    const int blocks = planes / 4;        // 4 planes per 256-thread block
    Blur_28243704938542_kernel<<<blocks, 256, 0, stream>>>(x, out);
}